// Round 5
// baseline (843.807 us; speedup 1.0000x reference)
//
#include <hip/hip_runtime.h>
#include <math.h>

#define N_NODES   50000
#define N_EDGES   800000
#define NUM_GRAPHS 64
#define FDIM      64
#define HDIM      64
#define NLAYERS   3
#define NCLASSES  16
#define EPS       1e-5f

#define SCAN_CHUNK 1024
#define NCHUNKS ((N_NODES + SCAN_CHUNK - 1) / SCAN_CHUNK)   // 49

// ---------------------------------------------------------------------------
// CSR build: degree histogram
__global__ void k_count(const int* __restrict__ dst, int* __restrict__ cnt) {
    int e = blockIdx.x * 256 + threadIdx.x;
    if (e < N_EDGES) atomicAdd(&cnt[dst[e]], 1);
}

__global__ void k_chunk_sums(const int* __restrict__ cnt, int* __restrict__ bsum,
                             float* __restrict__ logsum) {
    __shared__ int   ired[256];
    __shared__ float lred[256];
    int b = blockIdx.x, t = threadIdx.x;
    int base = b * SCAN_CHUNK;
    int s = 0; float ls = 0.f;
    for (int i = t; i < SCAN_CHUNK; i += 256) {
        int idx = base + i;
        if (idx < N_NODES) {
            int v = cnt[idx];
            s += v;
            ls += logf((float)v + 1.0f);
        }
    }
    ired[t] = s; lred[t] = ls;
    __syncthreads();
    for (int off = 128; off > 0; off >>= 1) {
        if (t < off) { ired[t] += ired[t + off]; lred[t] += lred[t + off]; }
        __syncthreads();
    }
    if (t == 0) { bsum[b] = ired[0]; atomicAdd(logsum, lred[0]); }
}

__global__ void k_scan_top(const int* __restrict__ bsum, int* __restrict__ boff,
                           int* __restrict__ row_start) {
    if (threadIdx.x == 0) {
        int acc = 0;
        for (int i = 0; i < NCHUNKS; ++i) { boff[i] = acc; acc += bsum[i]; }
        row_start[N_NODES] = acc;
    }
}

__global__ void k_scan_chunks(const int* __restrict__ cnt, const int* __restrict__ boff,
                              int* __restrict__ row_start, int* __restrict__ cursor) {
    __shared__ int tsum[256];
    int b = blockIdx.x, t = threadIdx.x;
    int base = b * SCAN_CHUNK + t * 4;
    int v[4]; int s = 0;
    #pragma unroll
    for (int i = 0; i < 4; ++i) {
        int idx = base + i;
        v[i] = (idx < N_NODES) ? cnt[idx] : 0;
        s += v[i];
    }
    tsum[t] = s;
    __syncthreads();
    for (int off = 1; off < 256; off <<= 1) {
        int val = (t >= off) ? tsum[t - off] : 0;
        __syncthreads();
        tsum[t] += val;
        __syncthreads();
    }
    int excl = boff[b] + tsum[t] - s;
    #pragma unroll
    for (int i = 0; i < 4; ++i) {
        int idx = base + i;
        if (idx < N_NODES) { row_start[idx] = excl; cursor[idx] = excl; }
        excl += v[i];
    }
}

__global__ void k_scatter(const int* __restrict__ src, const int* __restrict__ dst,
                          int* __restrict__ cursor, int* __restrict__ csr_src) {
    int e = blockIdx.x * 256 + threadIdx.x;
    if (e < N_EDGES) {
        int d = dst[e];
        int slot = atomicAdd(&cursor[d], 1);
        csr_src[slot] = src[e];
    }
}

__global__ void k_scal(const int* __restrict__ cnt, const float* __restrict__ logsum,
                       float* __restrict__ inv_deg, float* __restrict__ ampv,
                       float* __restrict__ attv) {
    int n = blockIdx.x * 256 + threadIdx.x;
    if (n < N_NODES) {
        float avg = logsum[0] / (float)N_NODES;
        float degf = fmaxf((float)cnt[n], 1.0f);
        inv_deg[n] = 1.0f / degf;
        float ld = logf(degf + 1.0f);
        ampv[n] = ld / avg;
        attv[n] = avg / ld;
    }
}

// ---------------------------------------------------------------------------
// Weight folding: Wk[l][k][c] = sum_j lin_w[l][c][j] * post_w[l][j][k]
__global__ __launch_bounds__(256) void k_comb(const float* __restrict__ post_w,
                                              const float* __restrict__ lin_w,
                                              float* __restrict__ Wk) {
    int t = threadIdx.x;
    int c  = t & 63;
    int kl = t >> 6;
    int l  = blockIdx.x / 208;
    int k  = (blockIdx.x % 208) * 4 + kl;
    const float* lw = lin_w + (size_t)l * 4096 + c * 64;
    const float* pw = post_w + (size_t)l * 53248 + k;
    float acc = 0.f;
    #pragma unroll 8
    for (int j = 0; j < 64; ++j)
        acc += lw[j] * pw[(size_t)j * 832];
    Wk[(size_t)l * 53248 + (size_t)k * 64 + c] = acc;
}

__global__ void k_bc(const float* __restrict__ post_b, const float* __restrict__ lin_b,
                     const float* __restrict__ lin_w, float* __restrict__ bcv) {
    int t = threadIdx.x;
    if (t < 192) {
        int l = t >> 6, c = t & 63;
        float acc = lin_b[l * 64 + c];
        for (int j = 0; j < 64; ++j)
            acc += lin_w[(size_t)l * 4096 + c * 64 + j] * post_b[l * 64 + j];
        bcv[l * 64 + c] = acc;
    }
}

// ---------------------------------------------------------------------------
// p = x @ Wi^T + pre_b ; q = x @ Wj^T  (conflict-free transposed staging)
__global__ __launch_bounds__(256) void k_pre(const float* __restrict__ x,
                                             const float* __restrict__ pre_w,
                                             const float* __restrict__ pre_b,
                                             float* __restrict__ p,
                                             float* __restrict__ q) {
    __shared__ float At[64][68];
    __shared__ float Wt[128][68];
    int t = threadIdx.x;
    int c4 = (t & 15) * 4;
    int r4 = (t >> 4) * 4;
    int rowBase = blockIdx.x * 64;
    int srow = t >> 2, skq = t & 3;

    #pragma unroll
    for (int pass = 0; pass < 4; ++pass) {
        int kk = (pass * 4 + skq) * 4;
        int row = rowBase + srow;
        float4 v = make_float4(0.f, 0.f, 0.f, 0.f);
        if (row < N_NODES) v = *(const float4*)&x[(size_t)row * 64 + kk];
        At[kk + 0][srow] = v.x;
        At[kk + 1][srow] = v.y;
        At[kk + 2][srow] = v.z;
        At[kk + 3][srow] = v.w;
    }
    for (int idx4 = t; idx4 < 2048; idx4 += 256) {
        int c = idx4 & 63, kq = idx4 >> 6;
        float4 v = *(const float4*)&pre_w[(size_t)c * 128 + kq * 4];
        Wt[kq * 4 + 0][c] = v.x;
        Wt[kq * 4 + 1][c] = v.y;
        Wt[kq * 4 + 2][c] = v.z;
        Wt[kq * 4 + 3][c] = v.w;
    }
    __syncthreads();

    float accp[4][4] = {{0}}, accq[4][4] = {{0}};
    #pragma unroll 4
    for (int kk = 0; kk < 64; ++kk) {
        float4 a  = *(const float4*)&At[kk][r4];
        float4 wp = *(const float4*)&Wt[kk][c4];
        float4 wq = *(const float4*)&Wt[64 + kk][c4];
        float av[4]  = {a.x, a.y, a.z, a.w};
        float wpv[4] = {wp.x, wp.y, wp.z, wp.w};
        float wqv[4] = {wq.x, wq.y, wq.z, wq.w};
        #pragma unroll
        for (int i = 0; i < 4; ++i)
            #pragma unroll
            for (int j = 0; j < 4; ++j) {
                accp[i][j] += av[i] * wpv[j];
                accq[i][j] += av[i] * wqv[j];
            }
    }
    float pb[4];
    #pragma unroll
    for (int j = 0; j < 4; ++j) pb[j] = pre_b[c4 + j];
    #pragma unroll
    for (int i = 0; i < 4; ++i) {
        int row = rowBase + r4 + i;
        if (row < N_NODES) {
            float4 vp = make_float4(accp[i][0] + pb[0], accp[i][1] + pb[1],
                                    accp[i][2] + pb[2], accp[i][3] + pb[3]);
            float4 vq = make_float4(accq[i][0], accq[i][1], accq[i][2], accq[i][3]);
            *(float4*)&p[row * 64 + c4] = vp;
            *(float4*)&q[row * 64 + c4] = vq;
        }
    }
}

// ---------------------------------------------------------------------------
// FUSED per-layer kernel:
//   Phase 1: aggregate this block's 64 nodes (wave w owns nodes [16w,16w+16))
//            -> write aggr rows (stays hot in this XCD's L2)
//   Phase 2: x_next = relu( [x|aggr|amp*aggr|att*aggr] @ Wk + bc )
//            (split-K over 4 waves, double-buffered private LDS, 8x8 tiles)
__global__ __launch_bounds__(256) void k_post(const float* __restrict__ x,
                                              const float* __restrict__ p,
                                              const float* __restrict__ q,
                                              const int* __restrict__ row_start,
                                              const int* __restrict__ csr_src,
                                              const float* __restrict__ inv_deg,
                                              const float* __restrict__ ampv,
                                              const float* __restrict__ attv,
                                              const float* __restrict__ Wk,
                                              const float* __restrict__ bc,
                                              float* __restrict__ aggr,
                                              float* __restrict__ xout) {
    __shared__ float smem[8448];
    int t = threadIdx.x;
    int w = t >> 6;
    int l = t & 63;
    int rowBase = blockIdx.x * 64;

    // ---- Phase 1: aggregation of own nodes ----
    {
        int nodeBase = rowBase + w * 16;
        for (int i = 0; i < 16; ++i) {
            int n = nodeBase + i;
            if (n >= N_NODES) break;
            float pv = p[n * 64 + l];
            int beg = row_start[n], end = row_start[n + 1];
            float sum = 0.f, sq = 0.f;
            float mn = INFINITY, mx = -INFINITY;
            int e = beg;
            for (; e + 7 < end; e += 8) {
                float qv[8];
                #pragma unroll
                for (int u = 0; u < 8; ++u) {
                    int s = csr_src[e + u];
                    qv[u] = q[(size_t)s * 64 + l];
                }
                #pragma unroll
                for (int u = 0; u < 8; ++u) {
                    float m = pv + qv[u];
                    sum += m; sq += m * m;
                    mn = fminf(mn, m); mx = fmaxf(mx, m);
                }
            }
            for (; e + 3 < end; e += 4) {
                float qv[4];
                #pragma unroll
                for (int u = 0; u < 4; ++u) {
                    int s = csr_src[e + u];
                    qv[u] = q[(size_t)s * 64 + l];
                }
                #pragma unroll
                for (int u = 0; u < 4; ++u) {
                    float m = pv + qv[u];
                    sum += m; sq += m * m;
                    mn = fminf(mn, m); mx = fmaxf(mx, m);
                }
            }
            for (; e < end; ++e) {
                int s = csr_src[e];
                float m = pv + q[(size_t)s * 64 + l];
                sum += m; sq += m * m;
                mn = fminf(mn, m); mx = fmaxf(mx, m);
            }
            float id = inv_deg[n];
            float mean = sum * id;
            float var  = fmaxf(sq * id - mean * mean, 0.f);
            float sd   = sqrtf(var + EPS);
            if (end <= beg) { mn = 0.f; mx = 0.f; }
            float* a = aggr + (size_t)n * 256;
            a[l]       = mean;
            a[64 + l]  = mn;
            a[128 + l] = mx;
            a[192 + l] = sd;
        }
    }
    __syncthreads();   // aggr rows of this block visible (L1 write-through)

    // ---- Phase 2: GEMM ----
    float* AtBase = smem + w * 2112;
    float* WtBase = smem + w * 2112 + 1088;

    int r8 = (l >> 3) * 8;
    int c8 = (l & 7) * 8;
    int srow = l >> 1;        // 0..31
    int skq  = l & 1;         // 0..1

    int g0 = rowBase + srow;
    int g1 = rowBase + srow + 32;
    bool v0 = g0 < N_NODES, v1 = g1 < N_NODES;
    float amp0 = v0 ? ampv[g0] : 0.f;
    float att0 = v0 ? attv[g0] : 0.f;
    float amp1 = v1 ? ampv[g1] : 0.f;
    float att1 = v1 ? attv[g1] : 0.f;

    float acc[8][8];
    #pragma unroll
    for (int i = 0; i < 8; ++i)
        #pragma unroll
        for (int j = 0; j < 8; ++j) acc[i][j] = 0.f;

    float4 bA0, bA1, bW0, bW1;

    auto loadCh = [&](int ch) {
        int kk = w * 208 + ch * 8 + skq * 4;
        float4 a0 = make_float4(0.f, 0.f, 0.f, 0.f);
        float4 a1 = a0;
        if (kk < 64) {
            if (v0) a0 = *(const float4*)&x[(size_t)g0 * 64 + kk];
            if (v1) a1 = *(const float4*)&x[(size_t)g1 * 64 + kk];
        } else {
            int o = (kk < 320) ? (kk - 64) : ((kk < 576) ? (kk - 320) : (kk - 576));
            if (v0) a0 = *(const float4*)&aggr[(size_t)g0 * 256 + o];
            if (v1) a1 = *(const float4*)&aggr[(size_t)g1 * 256 + o];
        }
        bA0 = a0; bA1 = a1;
        const float4* ws = (const float4*)(Wk + (size_t)(w * 208 + ch * 8) * 64);
        bW0 = ws[l];
        bW1 = ws[l + 64];
    };

    auto stageCh = [&](int ch, int buf) {
        int kk = w * 208 + ch * 8 + skq * 4;
        float s0, s1;
        if (kk < 320)      { s0 = 1.f;  s1 = 1.f;  }
        else if (kk < 576) { s0 = amp0; s1 = amp1; }
        else               { s0 = att0; s1 = att1; }
        float* a = AtBase + buf * 544;
        int kb = skq * 4;
        a[(kb + 0) * 68 + srow] = bA0.x * s0;
        a[(kb + 1) * 68 + srow] = bA0.y * s0;
        a[(kb + 2) * 68 + srow] = bA0.z * s0;
        a[(kb + 3) * 68 + srow] = bA0.w * s0;
        a[(kb + 0) * 68 + srow + 32] = bA1.x * s1;
        a[(kb + 1) * 68 + srow + 32] = bA1.y * s1;
        a[(kb + 2) * 68 + srow + 32] = bA1.z * s1;
        a[(kb + 3) * 68 + srow + 32] = bA1.w * s1;
        float4* wd = (float4*)(WtBase + buf * 512);
        wd[l] = bW0;
        wd[l + 64] = bW1;
    };

    loadCh(0);
    stageCh(0, 0);
    loadCh(1);

    for (int ch = 0; ch < 26; ++ch) {
        int buf = ch & 1;
        asm volatile("s_waitcnt lgkmcnt(0)" ::: "memory");
        const float* a = AtBase + buf * 544;
        const float* ww = WtBase + buf * 512;
        #pragma unroll
        for (int kk = 0; kk < 8; ++kk) {
            float4 a0 = *(const float4*)&a[kk * 68 + r8];
            float4 a1 = *(const float4*)&a[kk * 68 + r8 + 4];
            float4 w0 = *(const float4*)&ww[kk * 64 + c8];
            float4 w1 = *(const float4*)&ww[kk * 64 + c8 + 4];
            float av[8] = {a0.x, a0.y, a0.z, a0.w, a1.x, a1.y, a1.z, a1.w};
            float wv[8] = {w0.x, w0.y, w0.z, w0.w, w1.x, w1.y, w1.z, w1.w};
            #pragma unroll
            for (int i = 0; i < 8; ++i)
                #pragma unroll
                for (int j = 0; j < 8; ++j)
                    acc[i][j] += av[i] * wv[j];
        }
        if (ch < 25) {
            stageCh(ch + 1, buf ^ 1);
            if (ch < 24) loadCh(ch + 2);
        }
    }

    // tree combine of the 4 waves' partials; lane-major stride-65 (conflict-free)
    float* b0 = smem;
    float* b1 = smem + 4224;
    __syncthreads();
    if (w == 2) {
        #pragma unroll
        for (int i = 0; i < 8; ++i)
            #pragma unroll
            for (int j = 0; j < 8; ++j) b0[l * 65 + i * 8 + j] = acc[i][j];
    } else if (w == 3) {
        #pragma unroll
        for (int i = 0; i < 8; ++i)
            #pragma unroll
            for (int j = 0; j < 8; ++j) b1[l * 65 + i * 8 + j] = acc[i][j];
    }
    __syncthreads();
    if (w == 0) {
        #pragma unroll
        for (int i = 0; i < 8; ++i)
            #pragma unroll
            for (int j = 0; j < 8; ++j) acc[i][j] += b0[l * 65 + i * 8 + j];
    } else if (w == 1) {
        #pragma unroll
        for (int i = 0; i < 8; ++i)
            #pragma unroll
            for (int j = 0; j < 8; ++j) acc[i][j] += b1[l * 65 + i * 8 + j];
    }
    __syncthreads();
    if (w == 1) {
        #pragma unroll
        for (int i = 0; i < 8; ++i)
            #pragma unroll
            for (int j = 0; j < 8; ++j) b0[l * 65 + i * 8 + j] = acc[i][j];
    }
    __syncthreads();
    if (w == 0) {
        #pragma unroll
        for (int i = 0; i < 8; ++i)
            #pragma unroll
            for (int j = 0; j < 8; ++j) acc[i][j] += b0[l * 65 + i * 8 + j];
        float bias[8];
        #pragma unroll
        for (int j = 0; j < 8; ++j) bias[j] = bc[c8 + j];
        #pragma unroll
        for (int i = 0; i < 8; ++i) {
            int grow = rowBase + r8 + i;
            if (grow < N_NODES) {
                float4 o0 = make_float4(fmaxf(acc[i][0] + bias[0], 0.f),
                                        fmaxf(acc[i][1] + bias[1], 0.f),
                                        fmaxf(acc[i][2] + bias[2], 0.f),
                                        fmaxf(acc[i][3] + bias[3], 0.f));
                float4 o1 = make_float4(fmaxf(acc[i][4] + bias[4], 0.f),
                                        fmaxf(acc[i][5] + bias[5], 0.f),
                                        fmaxf(acc[i][6] + bias[6], 0.f),
                                        fmaxf(acc[i][7] + bias[7], 0.f));
                *(float4*)&xout[(size_t)grow * 64 + c8]     = o0;
                *(float4*)&xout[(size_t)grow * 64 + c8 + 4] = o1;
            }
        }
    }
}

// ---------------------------------------------------------------------------
__global__ __launch_bounds__(256) void k_pool(const float* __restrict__ x,
                                              const int* __restrict__ batch,
                                              float* __restrict__ g_sum,
                                              int* __restrict__ g_cnt) {
    int lane = threadIdx.x & 63;
    int wave = blockIdx.x * 4 + (threadIdx.x >> 6);
    const int NPW = 128;
    int beg = wave * NPW;
    if (beg >= N_NODES) return;
    int end = min(beg + NPW, N_NODES);
    float acc = 0.f;
    int cur = batch[beg];
    int c = 0;
    for (int n = beg; n < end; ++n) {
        int b = batch[n];
        if (b != cur) {
            atomicAdd(&g_sum[cur * 64 + lane], acc);
            if (lane == 0) atomicAdd(&g_cnt[cur], c);
            acc = 0.f; c = 0; cur = b;
        }
        acc += x[n * 64 + lane];
        ++c;
    }
    atomicAdd(&g_sum[cur * 64 + lane], acc);
    if (lane == 0) atomicAdd(&g_cnt[cur], c);
}

__global__ __launch_bounds__(256) void k_mlp(const float* __restrict__ g_sum,
                                             const int* __restrict__ g_cnt,
                                             const float* __restrict__ w1,
                                             const float* __restrict__ b1,
                                             const float* __restrict__ w2,
                                             const float* __restrict__ b2,
                                             float* __restrict__ out) {
    __shared__ float g[64][64];
    __shared__ float h[64][64];
    __shared__ float wT[64][65];
    int t = threadIdx.x;
    for (int idx = t; idx < 4096; idx += 256) {
        int gi = idx >> 6, c = idx & 63;
        float cntf = fmaxf((float)g_cnt[gi], 1.f);
        g[gi][c] = g_sum[idx] / cntf;
    }
    for (int idx = t; idx < 4096; idx += 256) {
        int c = idx >> 6, k = idx & 63;
        wT[k][c] = w1[c * 64 + k];
    }
    __syncthreads();
    for (int idx = t; idx < 4096; idx += 256) {
        int gi = idx >> 6, c = idx & 63;
        float acc = b1[c];
        for (int k = 0; k < 64; ++k) acc += g[gi][k] * wT[k][c];
        h[gi][c] = fmaxf(acc, 0.f);
    }
    __syncthreads();
    for (int idx = t; idx < 64 * NCLASSES; idx += 256) {
        int gi = idx >> 4, c = idx & 15;
        float acc = b2[c];
        for (int k = 0; k < 64; ++k) acc += h[gi][k] * w2[c * 64 + k];
        out[gi * NCLASSES + c] = acc;
    }
}

// ---------------------------------------------------------------------------
extern "C" void kernel_launch(void* const* d_in, const int* in_sizes, int n_in,
                              void* d_out, int out_size, void* d_ws, size_t ws_size,
                              hipStream_t stream) {
    const float* x      = (const float*)d_in[0];
    const int*   ei     = (const int*)d_in[1];
    const int*   batch  = (const int*)d_in[2];
    const float* pre_w  = (const float*)d_in[3];
    const float* pre_b  = (const float*)d_in[4];
    const float* post_w = (const float*)d_in[5];
    const float* post_b = (const float*)d_in[6];
    const float* lin_w  = (const float*)d_in[7];
    const float* lin_b  = (const float*)d_in[8];
    const float* mlp_w1 = (const float*)d_in[9];
    const float* mlp_b1 = (const float*)d_in[10];
    const float* mlp_w2 = (const float*)d_in[11];
    const float* mlp_b2 = (const float*)d_in[12];

    const int* src = ei;
    const int* dst = ei + N_EDGES;

    char* base = (char*)d_ws;
    size_t off = 0;
    auto alloc = [&](size_t bytes) -> void* {
        void* ptr = base + off;
        off += (bytes + 255) & ~(size_t)255;
        return ptr;
    };
    int*   cnt       = (int*)alloc(N_NODES * 4);
    int*   row_start = (int*)alloc((N_NODES + 1) * 4);
    int*   cursor    = (int*)alloc(N_NODES * 4);
    int*   csr_src   = (int*)alloc(N_EDGES * 4);
    int*   bsum      = (int*)alloc(64 * 4);
    int*   boff      = (int*)alloc(64 * 4);
    float* logsum    = (float*)alloc(16);
    float* inv_deg   = (float*)alloc(N_NODES * 4);
    float* ampv      = (float*)alloc(N_NODES * 4);
    float* attv      = (float*)alloc(N_NODES * 4);
    float* p         = (float*)alloc((size_t)N_NODES * 64 * 4);
    float* q         = (float*)alloc((size_t)N_NODES * 64 * 4);
    float* aggr      = (float*)alloc((size_t)N_NODES * 256 * 4);
    float* xb0       = (float*)alloc((size_t)N_NODES * 64 * 4);
    float* xb1       = (float*)alloc((size_t)N_NODES * 64 * 4);
    float* g_sum     = (float*)alloc(64 * 64 * 4);
    int*   g_cnt     = (int*)alloc(64 * 4);
    float* Wk        = (float*)alloc((size_t)3 * 832 * 64 * 4);
    float* bcv       = (float*)alloc(3 * 64 * 4);

    hipMemsetAsync(cnt, 0, N_NODES * 4, stream);
    hipMemsetAsync(logsum, 0, 16, stream);
    hipMemsetAsync(g_sum, 0, 64 * 64 * 4, stream);
    hipMemsetAsync(g_cnt, 0, 64 * 4, stream);

    k_comb<<<624, 256, 0, stream>>>(post_w, lin_w, Wk);
    k_bc<<<1, 256, 0, stream>>>(post_b, lin_b, lin_w, bcv);

    k_count<<<(N_EDGES + 255) / 256, 256, 0, stream>>>(dst, cnt);
    k_chunk_sums<<<NCHUNKS, 256, 0, stream>>>(cnt, bsum, logsum);
    k_scan_top<<<1, 64, 0, stream>>>(bsum, boff, row_start);
    k_scan_chunks<<<NCHUNKS, 256, 0, stream>>>(cnt, boff, row_start, cursor);
    k_scatter<<<(N_EDGES + 255) / 256, 256, 0, stream>>>(src, dst, cursor, csr_src);
    k_scal<<<(N_NODES + 255) / 256, 256, 0, stream>>>(cnt, logsum, inv_deg, ampv, attv);

    const int GEMM_BLOCKS = (N_NODES + 63) / 64;   // 782
    const float* xin = x;
    float* bufs[3] = {xb0, xb1, xb0};
    for (int l = 0; l < NLAYERS; ++l) {
        k_pre<<<GEMM_BLOCKS, 256, 0, stream>>>(xin, pre_w + (size_t)l * 64 * 128,
                                               pre_b + l * 64, p, q);
        float* xo = bufs[l];
        k_post<<<GEMM_BLOCKS, 256, 0, stream>>>(xin, p, q, row_start, csr_src,
                                                inv_deg, ampv, attv,
                                                Wk + (size_t)l * 53248,
                                                bcv + l * 64, aggr, xo);
        xin = xo;
    }

    int pool_waves = (N_NODES + 127) / 128;
    k_pool<<<(pool_waves + 3) / 4, 256, 0, stream>>>(xin, batch, g_sum, g_cnt);
    k_mlp<<<1, 256, 0, stream>>>(g_sum, g_cnt, mlp_w1, mlp_b1, mlp_w2, mlp_b2,
                                 (float*)d_out);
}

// Round 6
// 685.610 us; speedup vs baseline: 1.2307x; 1.2307x over previous
//
#include <hip/hip_runtime.h>
#include <math.h>

#define N_NODES   50000
#define N_EDGES   800000
#define NUM_GRAPHS 64
#define FDIM      64
#define HDIM      64
#define NLAYERS   3
#define NCLASSES  16
#define EPS       1e-5f

#define SCAN_CHUNK 1024
#define NCHUNKS ((N_NODES + SCAN_CHUNK - 1) / SCAN_CHUNK)   // 49

// ---------------------------------------------------------------------------
// Weight folding Wk = (lin_w @ post_w) K-major, bc = lin_b + lin_w@post_b,
// plus workspace zero-init (cnt, logsum) so no memsets are needed.
__global__ __launch_bounds__(256) void k_comb(const float* __restrict__ post_w,
                                              const float* __restrict__ lin_w,
                                              const float* __restrict__ post_b,
                                              const float* __restrict__ lin_b,
                                              float* __restrict__ Wk,
                                              float* __restrict__ bcv,
                                              int* __restrict__ cnt,
                                              float* __restrict__ logsum) {
    int b = blockIdx.x, t = threadIdx.x;
    int zi = b * 256 + t;
    if (zi < N_NODES) cnt[zi] = 0;
    if (zi == 0) *logsum = 0.f;

    if (b < 624) {
        int c  = t & 63;
        int kl = t >> 6;
        int l  = b / 208;
        int k  = (b % 208) * 4 + kl;
        const float* lw = lin_w + (size_t)l * 4096 + c * 64;
        const float* pw = post_w + (size_t)l * 53248 + k;
        float acc = 0.f;
        #pragma unroll 8
        for (int j = 0; j < 64; ++j)
            acc += lw[j] * pw[(size_t)j * 832];
        Wk[(size_t)l * 53248 + (size_t)k * 64 + c] = acc;
    } else if (t < 192) {
        int l = t >> 6, c = t & 63;
        float acc = lin_b[l * 64 + c];
        for (int j = 0; j < 64; ++j)
            acc += lin_w[(size_t)l * 4096 + c * 64 + j] * post_b[l * 64 + j];
        bcv[l * 64 + c] = acc;
    }
}

// ---------------------------------------------------------------------------
// CSR build: degree histogram
__global__ void k_count(const int* __restrict__ dst, int* __restrict__ cnt) {
    int e = blockIdx.x * 256 + threadIdx.x;
    if (e < N_EDGES) atomicAdd(&cnt[dst[e]], 1);
}

__global__ void k_chunk_sums(const int* __restrict__ cnt, int* __restrict__ bsum,
                             float* __restrict__ logsum) {
    __shared__ int   ired[256];
    __shared__ float lred[256];
    int b = blockIdx.x, t = threadIdx.x;
    int base = b * SCAN_CHUNK;
    int s = 0; float ls = 0.f;
    for (int i = t; i < SCAN_CHUNK; i += 256) {
        int idx = base + i;
        if (idx < N_NODES) {
            int v = cnt[idx];
            s += v;
            ls += logf((float)v + 1.0f);
        }
    }
    ired[t] = s; lred[t] = ls;
    __syncthreads();
    for (int off = 128; off > 0; off >>= 1) {
        if (t < off) { ired[t] += ired[t + off]; lred[t] += lred[t + off]; }
        __syncthreads();
    }
    if (t == 0) { bsum[b] = ired[0]; atomicAdd(logsum, lred[0]); }
}

__global__ void k_scan_top(const int* __restrict__ bsum, int* __restrict__ boff,
                           int* __restrict__ row_start) {
    if (threadIdx.x == 0) {
        int acc = 0;
        for (int i = 0; i < NCHUNKS; ++i) { boff[i] = acc; acc += bsum[i]; }
        row_start[N_NODES] = acc;
    }
}

__global__ void k_scan_chunks(const int* __restrict__ cnt, const int* __restrict__ boff,
                              int* __restrict__ row_start, int* __restrict__ cursor) {
    __shared__ int tsum[256];
    int b = blockIdx.x, t = threadIdx.x;
    int base = b * SCAN_CHUNK + t * 4;
    int v[4]; int s = 0;
    #pragma unroll
    for (int i = 0; i < 4; ++i) {
        int idx = base + i;
        v[i] = (idx < N_NODES) ? cnt[idx] : 0;
        s += v[i];
    }
    tsum[t] = s;
    __syncthreads();
    for (int off = 1; off < 256; off <<= 1) {
        int val = (t >= off) ? tsum[t - off] : 0;
        __syncthreads();
        tsum[t] += val;
        __syncthreads();
    }
    int excl = boff[b] + tsum[t] - s;
    #pragma unroll
    for (int i = 0; i < 4; ++i) {
        int idx = base + i;
        if (idx < N_NODES) { row_start[idx] = excl; cursor[idx] = excl; }
        excl += v[i];
    }
}

__global__ void k_scatter(const int* __restrict__ src, const int* __restrict__ dst,
                          int* __restrict__ cursor, int* __restrict__ csr_src) {
    int e = blockIdx.x * 256 + threadIdx.x;
    if (e < N_EDGES) {
        int d = dst[e];
        int slot = atomicAdd(&cursor[d], 1);
        csr_src[slot] = src[e];
    }
}

// per-node degree scalers; block 0 also zero-inits pooling accumulators
__global__ void k_scal(const int* __restrict__ cnt, const float* __restrict__ logsum,
                       float* __restrict__ inv_deg, float* __restrict__ ampv,
                       float* __restrict__ attv, float* __restrict__ g_sum,
                       int* __restrict__ g_cnt) {
    int n = blockIdx.x * 256 + threadIdx.x;
    if (blockIdx.x == 0) {
        for (int i = threadIdx.x; i < 4096; i += 256) g_sum[i] = 0.f;
        if (threadIdx.x < 64) g_cnt[threadIdx.x] = 0;
    }
    if (n < N_NODES) {
        float avg = logsum[0] / (float)N_NODES;
        float degf = fmaxf((float)cnt[n], 1.0f);
        inv_deg[n] = 1.0f / degf;
        float ld = logf(degf + 1.0f);
        ampv[n] = ld / avg;
        attv[n] = avg / ld;
    }
}

// ---------------------------------------------------------------------------
// p = x @ Wi^T + pre_b ; q = x @ Wj^T  (conflict-free transposed staging)
__global__ __launch_bounds__(256) void k_pre(const float* __restrict__ x,
                                             const float* __restrict__ pre_w,
                                             const float* __restrict__ pre_b,
                                             float* __restrict__ p,
                                             float* __restrict__ q) {
    __shared__ float At[64][68];
    __shared__ float Wt[128][68];
    int t = threadIdx.x;
    int c4 = (t & 15) * 4;
    int r4 = (t >> 4) * 4;
    int rowBase = blockIdx.x * 64;
    int srow = t >> 2, skq = t & 3;

    #pragma unroll
    for (int pass = 0; pass < 4; ++pass) {
        int kk = (pass * 4 + skq) * 4;
        int row = rowBase + srow;
        float4 v = make_float4(0.f, 0.f, 0.f, 0.f);
        if (row < N_NODES) v = *(const float4*)&x[(size_t)row * 64 + kk];
        At[kk + 0][srow] = v.x;
        At[kk + 1][srow] = v.y;
        At[kk + 2][srow] = v.z;
        At[kk + 3][srow] = v.w;
    }
    for (int idx4 = t; idx4 < 2048; idx4 += 256) {
        int c = idx4 & 63, kq = idx4 >> 6;
        float4 v = *(const float4*)&pre_w[(size_t)c * 128 + kq * 4];
        Wt[kq * 4 + 0][c] = v.x;
        Wt[kq * 4 + 1][c] = v.y;
        Wt[kq * 4 + 2][c] = v.z;
        Wt[kq * 4 + 3][c] = v.w;
    }
    __syncthreads();

    float accp[4][4] = {{0}}, accq[4][4] = {{0}};
    #pragma unroll 4
    for (int kk = 0; kk < 64; ++kk) {
        float4 a  = *(const float4*)&At[kk][r4];
        float4 wp = *(const float4*)&Wt[kk][c4];
        float4 wq = *(const float4*)&Wt[64 + kk][c4];
        float av[4]  = {a.x, a.y, a.z, a.w};
        float wpv[4] = {wp.x, wp.y, wp.z, wp.w};
        float wqv[4] = {wq.x, wq.y, wq.z, wq.w};
        #pragma unroll
        for (int i = 0; i < 4; ++i)
            #pragma unroll
            for (int j = 0; j < 4; ++j) {
                accp[i][j] += av[i] * wpv[j];
                accq[i][j] += av[i] * wqv[j];
            }
    }
    float pb[4];
    #pragma unroll
    for (int j = 0; j < 4; ++j) pb[j] = pre_b[c4 + j];
    #pragma unroll
    for (int i = 0; i < 4; ++i) {
        int row = rowBase + r4 + i;
        if (row < N_NODES) {
            float4 vp = make_float4(accp[i][0] + pb[0], accp[i][1] + pb[1],
                                    accp[i][2] + pb[2], accp[i][3] + pb[3]);
            float4 vq = make_float4(accq[i][0], accq[i][1], accq[i][2], accq[i][3]);
            *(float4*)&p[row * 64 + c4] = vp;
            *(float4*)&q[row * 64 + c4] = vq;
        }
    }
}

// ---------------------------------------------------------------------------
// Aggregation: one wave per node, lane = channel, 8 gathers in flight.
// Aggregates q only: mean = p + Eq, var = E[q^2]-E[q]^2, min/max = p + min/max q
__global__ __launch_bounds__(256) void k_aggr(const float* __restrict__ p,
                                              const float* __restrict__ q,
                                              const int* __restrict__ row_start,
                                              const int* __restrict__ csr_src,
                                              const float* __restrict__ inv_deg,
                                              float* __restrict__ aggr) {
    int wid  = (blockIdx.x * 256 + threadIdx.x) >> 6;
    int lane = threadIdx.x & 63;
    if (wid >= N_NODES) return;
    int n = wid;
    int beg = row_start[n], end = row_start[n + 1];
    float sum = 0.f, sq = 0.f;
    float mn = INFINITY, mx = -INFINITY;
    int e = beg;
    for (; e + 7 < end; e += 8) {
        float qv[8];
        #pragma unroll
        for (int u = 0; u < 8; ++u) {
            int s = csr_src[e + u];
            qv[u] = q[(size_t)s * 64 + lane];
        }
        #pragma unroll
        for (int u = 0; u < 8; ++u) {
            float m = qv[u];
            sum += m; sq += m * m;
            mn = fminf(mn, m); mx = fmaxf(mx, m);
        }
    }
    for (; e + 3 < end; e += 4) {
        float qv[4];
        #pragma unroll
        for (int u = 0; u < 4; ++u) {
            int s = csr_src[e + u];
            qv[u] = q[(size_t)s * 64 + lane];
        }
        #pragma unroll
        for (int u = 0; u < 4; ++u) {
            float m = qv[u];
            sum += m; sq += m * m;
            mn = fminf(mn, m); mx = fmaxf(mx, m);
        }
    }
    for (; e < end; ++e) {
        int s = csr_src[e];
        float m = q[(size_t)s * 64 + lane];
        sum += m; sq += m * m;
        mn = fminf(mn, m); mx = fmaxf(mx, m);
    }
    float* a = aggr + (size_t)n * 256;
    if (end <= beg) {
        a[lane]       = 0.f;
        a[64 + lane]  = 0.f;
        a[128 + lane] = 0.f;
        a[192 + lane] = sqrtf(EPS);
    } else {
        float pv = p[n * 64 + lane];
        float id = inv_deg[n];
        float meanq = sum * id;
        float var = fmaxf(sq * id - meanq * meanq, 0.f);
        a[lane]       = pv + meanq;
        a[64 + lane]  = pv + mn;
        a[128 + lane] = pv + mx;
        a[192 + lane] = sqrtf(var + EPS);
    }
}

// ---------------------------------------------------------------------------
// x_next = relu( A @ Wk + bc ),  A = [x | aggr | amp*aggr | att*aggr]  [N,832]
// Split-K across 4 waves (52 kk-chunks of 8, wave w owns 26), per-wave private
// double-buffered LDS staging, single register buffer set, software pipeline.
__global__ __launch_bounds__(256) void k_post(const float* __restrict__ x,
                                              const float* __restrict__ aggr,
                                              const float* __restrict__ ampv,
                                              const float* __restrict__ attv,
                                              const float* __restrict__ Wk,
                                              const float* __restrict__ bc,
                                              float* __restrict__ xout) {
    __shared__ float smem[8448];
    int t = threadIdx.x;
    int w = t >> 6;
    int l = t & 63;
    float* AtBase = smem + w * 2112;
    float* WtBase = smem + w * 2112 + 1088;
    int rowBase = blockIdx.x * 64;

    int r8 = (l >> 3) * 8;
    int c8 = (l & 7) * 8;
    int srow = l >> 1;        // 0..31
    int skq  = l & 1;         // 0..1

    int g0 = rowBase + srow;
    int g1 = rowBase + srow + 32;
    bool v0 = g0 < N_NODES, v1 = g1 < N_NODES;
    float amp0 = v0 ? ampv[g0] : 0.f;
    float att0 = v0 ? attv[g0] : 0.f;
    float amp1 = v1 ? ampv[g1] : 0.f;
    float att1 = v1 ? attv[g1] : 0.f;

    float acc[8][8];
    #pragma unroll
    for (int i = 0; i < 8; ++i)
        #pragma unroll
        for (int j = 0; j < 8; ++j) acc[i][j] = 0.f;

    float4 bA0, bA1, bW0, bW1;

    auto loadCh = [&](int ch) {
        int kk = w * 208 + ch * 8 + skq * 4;
        float4 a0 = make_float4(0.f, 0.f, 0.f, 0.f);
        float4 a1 = a0;
        if (kk < 64) {
            if (v0) a0 = *(const float4*)&x[(size_t)g0 * 64 + kk];
            if (v1) a1 = *(const float4*)&x[(size_t)g1 * 64 + kk];
        } else {
            int o = (kk < 320) ? (kk - 64) : ((kk < 576) ? (kk - 320) : (kk - 576));
            if (v0) a0 = *(const float4*)&aggr[(size_t)g0 * 256 + o];
            if (v1) a1 = *(const float4*)&aggr[(size_t)g1 * 256 + o];
        }
        bA0 = a0; bA1 = a1;
        const float4* ws = (const float4*)(Wk + (size_t)(w * 208 + ch * 8) * 64);
        bW0 = ws[l];
        bW1 = ws[l + 64];
    };

    auto stageCh = [&](int ch, int buf) {
        int kk = w * 208 + ch * 8 + skq * 4;
        float s0, s1;
        if (kk < 320)      { s0 = 1.f;  s1 = 1.f;  }
        else if (kk < 576) { s0 = amp0; s1 = amp1; }
        else               { s0 = att0; s1 = att1; }
        float* a = AtBase + buf * 544;
        int kb = skq * 4;
        a[(kb + 0) * 68 + srow] = bA0.x * s0;
        a[(kb + 1) * 68 + srow] = bA0.y * s0;
        a[(kb + 2) * 68 + srow] = bA0.z * s0;
        a[(kb + 3) * 68 + srow] = bA0.w * s0;
        a[(kb + 0) * 68 + srow + 32] = bA1.x * s1;
        a[(kb + 1) * 68 + srow + 32] = bA1.y * s1;
        a[(kb + 2) * 68 + srow + 32] = bA1.z * s1;
        a[(kb + 3) * 68 + srow + 32] = bA1.w * s1;
        float4* wd = (float4*)(WtBase + buf * 512);
        wd[l] = bW0;
        wd[l + 64] = bW1;
    };

    loadCh(0);
    stageCh(0, 0);
    loadCh(1);

    for (int ch = 0; ch < 26; ++ch) {
        int buf = ch & 1;
        asm volatile("s_waitcnt lgkmcnt(0)" ::: "memory");
        const float* a = AtBase + buf * 544;
        const float* ww = WtBase + buf * 512;
        #pragma unroll
        for (int kk = 0; kk < 8; ++kk) {
            float4 a0 = *(const float4*)&a[kk * 68 + r8];
            float4 a1 = *(const float4*)&a[kk * 68 + r8 + 4];
            float4 w0 = *(const float4*)&ww[kk * 64 + c8];
            float4 w1 = *(const float4*)&ww[kk * 64 + c8 + 4];
            float av[8] = {a0.x, a0.y, a0.z, a0.w, a1.x, a1.y, a1.z, a1.w};
            float wv[8] = {w0.x, w0.y, w0.z, w0.w, w1.x, w1.y, w1.z, w1.w};
            #pragma unroll
            for (int i = 0; i < 8; ++i)
                #pragma unroll
                for (int j = 0; j < 8; ++j)
                    acc[i][j] += av[i] * wv[j];
        }
        if (ch < 25) {
            stageCh(ch + 1, buf ^ 1);
            if (ch < 24) loadCh(ch + 2);
        }
    }

    // tree combine of the 4 waves' partials; lane-major stride-65 (conflict-free)
    float* b0 = smem;
    float* b1 = smem + 4224;
    __syncthreads();
    if (w == 2) {
        #pragma unroll
        for (int i = 0; i < 8; ++i)
            #pragma unroll
            for (int j = 0; j < 8; ++j) b0[l * 65 + i * 8 + j] = acc[i][j];
    } else if (w == 3) {
        #pragma unroll
        for (int i = 0; i < 8; ++i)
            #pragma unroll
            for (int j = 0; j < 8; ++j) b1[l * 65 + i * 8 + j] = acc[i][j];
    }
    __syncthreads();
    if (w == 0) {
        #pragma unroll
        for (int i = 0; i < 8; ++i)
            #pragma unroll
            for (int j = 0; j < 8; ++j) acc[i][j] += b0[l * 65 + i * 8 + j];
    } else if (w == 1) {
        #pragma unroll
        for (int i = 0; i < 8; ++i)
            #pragma unroll
            for (int j = 0; j < 8; ++j) acc[i][j] += b1[l * 65 + i * 8 + j];
    }
    __syncthreads();
    if (w == 1) {
        #pragma unroll
        for (int i = 0; i < 8; ++i)
            #pragma unroll
            for (int j = 0; j < 8; ++j) b0[l * 65 + i * 8 + j] = acc[i][j];
    }
    __syncthreads();
    if (w == 0) {
        #pragma unroll
        for (int i = 0; i < 8; ++i)
            #pragma unroll
            for (int j = 0; j < 8; ++j) acc[i][j] += b0[l * 65 + i * 8 + j];
        float bias[8];
        #pragma unroll
        for (int j = 0; j < 8; ++j) bias[j] = bc[c8 + j];
        #pragma unroll
        for (int i = 0; i < 8; ++i) {
            int grow = rowBase + r8 + i;
            if (grow < N_NODES) {
                float4 o0 = make_float4(fmaxf(acc[i][0] + bias[0], 0.f),
                                        fmaxf(acc[i][1] + bias[1], 0.f),
                                        fmaxf(acc[i][2] + bias[2], 0.f),
                                        fmaxf(acc[i][3] + bias[3], 0.f));
                float4 o1 = make_float4(fmaxf(acc[i][4] + bias[4], 0.f),
                                        fmaxf(acc[i][5] + bias[5], 0.f),
                                        fmaxf(acc[i][6] + bias[6], 0.f),
                                        fmaxf(acc[i][7] + bias[7], 0.f));
                *(float4*)&xout[(size_t)grow * 64 + c8]     = o0;
                *(float4*)&xout[(size_t)grow * 64 + c8 + 4] = o1;
            }
        }
    }
}

// ---------------------------------------------------------------------------
__global__ __launch_bounds__(256) void k_pool(const float* __restrict__ x,
                                              const int* __restrict__ batch,
                                              float* __restrict__ g_sum,
                                              int* __restrict__ g_cnt) {
    int lane = threadIdx.x & 63;
    int wave = blockIdx.x * 4 + (threadIdx.x >> 6);
    const int NPW = 128;
    int beg = wave * NPW;
    if (beg >= N_NODES) return;
    int end = min(beg + NPW, N_NODES);
    float acc = 0.f;
    int cur = batch[beg];
    int c = 0;
    for (int n = beg; n < end; ++n) {
        int b = batch[n];
        if (b != cur) {
            atomicAdd(&g_sum[cur * 64 + lane], acc);
            if (lane == 0) atomicAdd(&g_cnt[cur], c);
            acc = 0.f; c = 0; cur = b;
        }
        acc += x[n * 64 + lane];
        ++c;
    }
    atomicAdd(&g_sum[cur * 64 + lane], acc);
    if (lane == 0) atomicAdd(&g_cnt[cur], c);
}

__global__ __launch_bounds__(256) void k_mlp(const float* __restrict__ g_sum,
                                             const int* __restrict__ g_cnt,
                                             const float* __restrict__ w1,
                                             const float* __restrict__ b1,
                                             const float* __restrict__ w2,
                                             const float* __restrict__ b2,
                                             float* __restrict__ out) {
    __shared__ float g[64][64];
    __shared__ float h[64][64];
    __shared__ float wT[64][65];
    int t = threadIdx.x;
    for (int idx = t; idx < 4096; idx += 256) {
        int gi = idx >> 6, c = idx & 63;
        float cntf = fmaxf((float)g_cnt[gi], 1.f);
        g[gi][c] = g_sum[idx] / cntf;
    }
    for (int idx = t; idx < 4096; idx += 256) {
        int c = idx >> 6, k = idx & 63;
        wT[k][c] = w1[c * 64 + k];
    }
    __syncthreads();
    for (int idx = t; idx < 4096; idx += 256) {
        int gi = idx >> 6, c = idx & 63;
        float acc = b1[c];
        for (int k = 0; k < 64; ++k) acc += g[gi][k] * wT[k][c];
        h[gi][c] = fmaxf(acc, 0.f);
    }
    __syncthreads();
    for (int idx = t; idx < 64 * NCLASSES; idx += 256) {
        int gi = idx >> 4, c = idx & 15;
        float acc = b2[c];
        for (int k = 0; k < 64; ++k) acc += h[gi][k] * w2[c * 64 + k];
        out[gi * NCLASSES + c] = acc;
    }
}

// ---------------------------------------------------------------------------
extern "C" void kernel_launch(void* const* d_in, const int* in_sizes, int n_in,
                              void* d_out, int out_size, void* d_ws, size_t ws_size,
                              hipStream_t stream) {
    const float* x      = (const float*)d_in[0];
    const int*   ei     = (const int*)d_in[1];
    const int*   batch  = (const int*)d_in[2];
    const float* pre_w  = (const float*)d_in[3];
    const float* pre_b  = (const float*)d_in[4];
    const float* post_w = (const float*)d_in[5];
    const float* post_b = (const float*)d_in[6];
    const float* lin_w  = (const float*)d_in[7];
    const float* lin_b  = (const float*)d_in[8];
    const float* mlp_w1 = (const float*)d_in[9];
    const float* mlp_b1 = (const float*)d_in[10];
    const float* mlp_w2 = (const float*)d_in[11];
    const float* mlp_b2 = (const float*)d_in[12];

    const int* src = ei;
    const int* dst = ei + N_EDGES;

    char* base = (char*)d_ws;
    size_t off = 0;
    auto alloc = [&](size_t bytes) -> void* {
        void* ptr = base + off;
        off += (bytes + 255) & ~(size_t)255;
        return ptr;
    };
    int*   cnt       = (int*)alloc(N_NODES * 4);
    int*   row_start = (int*)alloc((N_NODES + 1) * 4);
    int*   cursor    = (int*)alloc(N_NODES * 4);
    int*   csr_src   = (int*)alloc(N_EDGES * 4);
    int*   bsum      = (int*)alloc(64 * 4);
    int*   boff      = (int*)alloc(64 * 4);
    float* logsum    = (float*)alloc(16);
    float* inv_deg   = (float*)alloc(N_NODES * 4);
    float* ampv      = (float*)alloc(N_NODES * 4);
    float* attv      = (float*)alloc(N_NODES * 4);
    float* p         = (float*)alloc((size_t)N_NODES * 64 * 4);
    float* q         = (float*)alloc((size_t)N_NODES * 64 * 4);
    float* aggr      = (float*)alloc((size_t)N_NODES * 256 * 4);
    float* xb0       = (float*)alloc((size_t)N_NODES * 64 * 4);
    float* xb1       = (float*)alloc((size_t)N_NODES * 64 * 4);
    float* g_sum     = (float*)alloc(64 * 64 * 4);
    int*   g_cnt     = (int*)alloc(64 * 4);
    float* Wk        = (float*)alloc((size_t)3 * 832 * 64 * 4);
    float* bcv       = (float*)alloc(3 * 64 * 4);

    // weight folding + workspace zero-init (no memsets needed)
    k_comb<<<625, 256, 0, stream>>>(post_w, lin_w, post_b, lin_b, Wk, bcv,
                                    cnt, logsum);

    k_count<<<(N_EDGES + 255) / 256, 256, 0, stream>>>(dst, cnt);
    k_chunk_sums<<<NCHUNKS, 256, 0, stream>>>(cnt, bsum, logsum);
    k_scan_top<<<1, 64, 0, stream>>>(bsum, boff, row_start);
    k_scan_chunks<<<NCHUNKS, 256, 0, stream>>>(cnt, boff, row_start, cursor);
    k_scatter<<<(N_EDGES + 255) / 256, 256, 0, stream>>>(src, dst, cursor, csr_src);
    k_scal<<<(N_NODES + 255) / 256, 256, 0, stream>>>(cnt, logsum, inv_deg,
                                                      ampv, attv, g_sum, g_cnt);

    const int GEMM_BLOCKS = (N_NODES + 63) / 64;   // 782
    const float* xin = x;
    float* bufs[3] = {xb0, xb1, xb0};
    for (int l = 0; l < NLAYERS; ++l) {
        k_pre<<<GEMM_BLOCKS, 256, 0, stream>>>(xin, pre_w + (size_t)l * 64 * 128,
                                               pre_b + l * 64, p, q);
        k_aggr<<<(N_NODES + 3) / 4, 256, 0, stream>>>(p, q, row_start, csr_src,
                                                      inv_deg, aggr);
        float* xo = bufs[l];
        k_post<<<GEMM_BLOCKS, 256, 0, stream>>>(xin, aggr, ampv, attv,
                                                Wk + (size_t)l * 53248,
                                                bcv + l * 64, xo);
        xin = xo;
    }

    int pool_waves = (N_NODES + 127) / 128;
    k_pool<<<(pool_waves + 3) / 4, 256, 0, stream>>>(xin, batch, g_sum, g_cnt);
    k_mlp<<<1, 256, 0, stream>>>(g_sum, g_cnt, mlp_w1, mlp_b1, mlp_w2, mlp_b2,
                                 (float*)d_out);
}